// Round 4
// baseline (630.091 us; speedup 1.0000x reference)
//
#include <hip/hip_runtime.h>
#include <math.h>
#include <stdint.h>

constexpr int B = 2, S = 4096, D = 1024, H = 16, DK = 64;
constexpr int M_TOT = B * S; // 8192

typedef __attribute__((ext_vector_type(8))) short bf16x8;
typedef __attribute__((ext_vector_type(4))) float f32x4;
typedef __attribute__((ext_vector_type(4))) uint32_t u32x4;
typedef unsigned short u16;

// fp32 -> bf16 round-to-nearest-even (manual, always correct)
__device__ inline u16 f2bf(float f) {
    uint32_t u = __builtin_bit_cast(uint32_t, f);
    u += 0x7fffu + ((u >> 16) & 1u);
    return (u16)(u >> 16);
}

// fp32 -> bf16 via native __bf16 (gfx950 v_cvt_pk_bf16_f32 path)
__device__ inline u16 f2bf_hw(float f) {
    __bf16 h = (__bf16)f;
    return __builtin_bit_cast(u16, h);
}

// async global->LDS, 16B per lane. lds base must be wave-uniform.
__device__ inline void gl2lds16(const void* g, void* l) {
    __builtin_amdgcn_global_load_lds((const __attribute__((address_space(1))) void*)g,
                                     (__attribute__((address_space(3))) void*)l, 16, 0, 0);
}

// ---------------------------------------------------------------------------
// fp32 -> bf16 conversion; blockIdx.y selects tensor.
// ---------------------------------------------------------------------------
__global__ __launch_bounds__(256) void conv_bf16(const float* __restrict__ s0, const float* __restrict__ s1,
                                                 const float* __restrict__ s2, const float* __restrict__ s3,
                                                 u16* __restrict__ d0, u16* __restrict__ d1,
                                                 u16* __restrict__ d2, u16* __restrict__ d3, int n) {
    const float* s; u16* d;
    switch (blockIdx.y) {
        case 0: s = s0; d = d0; break;
        case 1: s = s1; d = d1; break;
        case 2: s = s2; d = d2; break;
        default: s = s3; d = d3; break;
    }
    const int i = (blockIdx.x * 256 + threadIdx.x) * 4;
    if (i < n) {
        float4 v = *(const float4*)(s + i);
        ushort4 o;
        o.x = f2bf(v.x); o.y = f2bf(v.y); o.z = f2bf(v.z); o.w = f2bf(v.w);
        *(ushort4*)(d + i) = o;
    }
}

// int32 mask [S,S] -> bitmask, bit c of u64 word (q*64+t) = mask[q][t*64+c]
__global__ __launch_bounds__(256) void mask_pack(const int* __restrict__ m, uint32_t* __restrict__ out) {
    const int i = blockIdx.x * 256 + threadIdx.x;  // one u32 = 32 keys
    const int base = i * 32;
    uint32_t b = 0;
#pragma unroll
    for (int j = 0; j < 32; ++j) b |= (m[base + j] != 0 ? 1u : 0u) << j;
    out[i] = b;
}

// ---------------------------------------------------------------------------
// bf16 GEMM: Y[i][j] = oscale * sum_k X[i][k] * W[j][k]
// 128x128 tile, 4 waves in 2x2, BK=64. T3 "minimum 2-phase": double-buffered
// LDS (64 KB -- free at 2 blocks/CU), STAGE(next) issued BEFORE COMPUTE(cur),
// one vmcnt(0)+s_barrier AFTER compute so global_load_lds latency hides under
// the MFMAs.
// ---------------------------------------------------------------------------
template <typename OutT>
__global__ __launch_bounds__(256) void gemm_bt(const u16* __restrict__ X, const u16* __restrict__ Wm,
                                               OutT* __restrict__ Y, int M, int N, int K, float oscale) {
    __shared__ u16 As[2][128 * 64];
    __shared__ u16 Bs[2][128 * 64];
    const int tid = threadIdx.x;
    const int lane = tid & 63;
    const int wave = tid >> 6;
    const int l15 = lane & 15;
    const int quad = lane >> 4;
    const int i0 = blockIdx.x * 128;
    const int j0 = blockIdx.y * 128;
    const int wm = wave & 1, wn = wave >> 1;
    const int lr = lane >> 3;        // row within 8-row chunk
    const int lc = (lane & 7) * 8;   // k offset within 64

    f32x4 zero = {0.f, 0.f, 0.f, 0.f};
    f32x4 acc[4][4];
#pragma unroll
    for (int a = 0; a < 4; ++a)
#pragma unroll
        for (int b2 = 0; b2 < 4; ++b2) acc[a][b2] = zero;

    auto STAGE = [&](int buf, int k0) {
#pragma unroll
        for (int c = 0; c < 4; ++c) {
            const int ch = wave * 4 + c;          // 0..15
            const int row = ch * 8 + lr;          // 0..127
            gl2lds16(X + (size_t)(i0 + row) * K + k0 + lc, &As[buf][ch * 512]);
            gl2lds16(Wm + (size_t)(j0 + row) * K + k0 + lc, &Bs[buf][ch * 512]);
        }
    };

    auto COMPUTE = [&](int buf) {
        bf16x8 af[4][2];
#pragma unroll
        for (int mt = 0; mt < 4; ++mt)
#pragma unroll
            for (int ks = 0; ks < 2; ++ks)
                af[mt][ks] = *(const bf16x8*)&As[buf][(wm * 64 + mt * 16 + l15) * 64 + ks * 32 + quad * 8];
#pragma unroll
        for (int nt = 0; nt < 4; ++nt) {
#pragma unroll
            for (int ks = 0; ks < 2; ++ks) {
                bf16x8 bfr = *(const bf16x8*)&Bs[buf][(wn * 64 + nt * 16 + l15) * 64 + ks * 32 + quad * 8];
#pragma unroll
                for (int mt = 0; mt < 4; ++mt)
                    acc[mt][nt] = __builtin_amdgcn_mfma_f32_16x16x32_bf16(af[mt][ks], bfr, acc[mt][nt], 0, 0, 0);
            }
        }
    };

    const int KT = K >> 6;   // all call sites: K=1024 -> 16 (even)
    STAGE(0, 0);
    asm volatile("s_waitcnt vmcnt(0)" ::: "memory");
    __builtin_amdgcn_s_barrier();
    __builtin_amdgcn_sched_barrier(0);
    for (int t = 0; t < KT; t += 2) {
        if (t + 1 < KT) STAGE(1, (t + 1) << 6);
        COMPUTE(0);
        asm volatile("s_waitcnt vmcnt(0)" ::: "memory");
        __builtin_amdgcn_s_barrier();
        __builtin_amdgcn_sched_barrier(0);
        if (t + 2 < KT) STAGE(0, (t + 2) << 6);
        if (t + 1 < KT) {
            COMPUTE(1);
            asm volatile("s_waitcnt vmcnt(0)" ::: "memory");
            __builtin_amdgcn_s_barrier();
            __builtin_amdgcn_sched_barrier(0);
        }
    }

#pragma unroll
    for (int mt = 0; mt < 4; ++mt) {
#pragma unroll
        for (int r = 0; r < 4; ++r) {
            const int gi = i0 + wm * 64 + mt * 16 + quad * 4 + r;
#pragma unroll
            for (int nt = 0; nt < 4; ++nt) {
                const int gj = j0 + wn * 64 + nt * 16 + l15;
                const float v = acc[mt][nt][r] * oscale;
                if constexpr (sizeof(OutT) == 2) {
                    Y[(size_t)gi * N + gj] = (OutT)f2bf(v);
                } else {
                    Y[(size_t)gi * N + gj] = v;
                }
            }
        }
    }
}

// ---------------------------------------------------------------------------
// Flash attention, bf16 MFMA, static-shift softmax (p = exp2(s), shift
// cancels in 1/l normalize; row sums via all-ones MFMA column).
// Grid: (S/128, B*H). 4 waves; each wave owns 32 q-rows (2 m-frags).
//
// SWAPPED QK^T (S^T = mfma(K, Q)): lane holds P for one q-row (col = l15);
// packed bf16 pairs form the PV A-fragments directly (V's key dim bit-permuted
// in LDS: phys block cb holds keys {32*(cb>>2)+4*(cb&3)+0..3, +16..+19}).
// P never touches LDS.
//
// This round:
//  - K NEVER STAGED: all 4 waves need identical kf fragments and they map to
//    contiguous 16B global loads -> load kf straight from (L2-resident) global.
//    kf for tile t+1 is issued right after tile t's QK (kf dead after QK), so
//    L2 latency hides under softmax+PV. Removes K ds_writes + 8 ds_read_b128
//    per lane*tile (half the bank-conflict surface).
//  - Vs DOUBLE-BUFFERED -> ONE barrier per tile (write t+1 into buf^1 overlaps
//    compute of t; readers of buf^1 finished before the previous barrier).
//  - V swizzle/addressing reverted to round-2 exact form (known 128cy/tile;
//    the round-3 SWZ variant tripled conflicts).
//  - T14 reg staging (V+mask), raw barriers, no vmcnt drain; T5 setprio;
//    XCD-aware (q0,bh) remap: each XCD owns 4 heads' K/V (L2-resident).
// ---------------------------------------------------------------------------
struct KVStage {
    uint64_t rva[2], rvb[2];
    uint64_t rm[2];
};

__global__ __launch_bounds__(256) void attn_mfma(const u16* __restrict__ Qb, const u16* __restrict__ Kb,
                                                 const u16* __restrict__ Vt,
                                                 const uint64_t* __restrict__ mask64,
                                                 u16* __restrict__ ctx) {
    __shared__ u16 Vs[2][64 * 64];       // [dv][key], keys bit-permuted, col-blocks swizzled
    const int tid = threadIdx.x;
    const int lane = tid & 63;
    const int wave = tid >> 6;
    const int l15 = lane & 15;
    const int quad = lane >> 4;

    // XCD-aware remap: consecutive-dispatch blocks round-robin XCDs (bid&7);
    // give each XCD a contiguous group of 4 heads so K/V panels stay in its L2.
    const int bid = blockIdx.y * (S / 128) + blockIdx.x;   // 0..1023
    const int xcd = bid & 7;
    const int loc = bid >> 3;            // 0..127
    const int bh = xcd * 4 + (loc >> 5); // 0..31
    const int q0 = (loc & 31) * 128;

    const int bb = bh >> 4, hh = bh & 15;
    const int mbase = bb * S;
    const int e0 = hh * DK;
    const int r7 = l15 & 7;

    // staging mapping: thread -> (row, col-block)
    const int srow = tid >> 2;           // 0..63
    const int scb = tid & 3;             // 0..3 (+4 on second iter)

    // Q fragments (B-operand: col = l15 = q-row, k = dk). Q pre-scaled by
    // (1/sqrt(DK))*log2(e).
    bf16x8 aq[2][2];
#pragma unroll
    for (int mi = 0; mi < 2; ++mi) {
        const u16* qrow = Qb + (size_t)(mbase + q0 + wave * 32 + mi * 16 + l15) * D + e0;
        aq[mi][0] = *(const bf16x8*)(qrow + quad * 8);
        aq[mi][1] = *(const bf16x8*)(qrow + 32 + quad * 8);
    }

    f32x4 O[2][4];
    f32x4 Ol[2];
#pragma unroll
    for (int mi = 0; mi < 2; ++mi) {
        Ol[mi] = (f32x4){0.f, 0.f, 0.f, 0.f};
#pragma unroll
        for (int dt = 0; dt < 4; ++dt) O[mi][dt] = (f32x4){0.f, 0.f, 0.f, 0.f};
    }

    bf16x8 ONES;
#pragma unroll
    for (int i = 0; i < 8; ++i) ONES[i] = (short)0x3F80;  // bf16 1.0

    // one mask u64 per q-row per K-tile (lane's q-row = l15)
    const uint64_t* mrow[2];
#pragma unroll
    for (int mi = 0; mi < 2; ++mi)
        mrow[mi] = mask64 + (size_t)(q0 + wave * 32 + mi * 16 + l15) * (S / 64);

    // K fragments for the current tile, loaded directly from global (L2-hit).
    bf16x8 kf[4][2];
    auto KFLOAD = [&](int kt) {
        const int kb = kt * 64;
#pragma unroll
        for (int nt = 0; nt < 4; ++nt) {
            const u16* krow = Kb + (size_t)(mbase + kb + nt * 16 + l15) * D + e0;
            kf[nt][0] = *(const bf16x8*)(krow + quad * 8);
            kf[nt][1] = *(const bf16x8*)(krow + 32 + quad * 8);
        }
    };

    auto LOADV = [&](KVStage& st, int kt) {
        const int kb = kt * 64;
#pragma unroll
        for (int it = 0; it < 2; ++it) {
            const int cb = scb + it * 4;
            const int k0v = 32 * (cb >> 2) + 4 * (cb & 3);
            const u16* vsrc = Vt + (size_t)(e0 + srow) * M_TOT + mbase + kb + k0v;
            st.rva[it] = *(const uint64_t*)(vsrc);
            st.rvb[it] = *(const uint64_t*)(vsrc + 16);
        }
#pragma unroll
        for (int mi = 0; mi < 2; ++mi) st.rm[mi] = mrow[mi][kt];
    };

    auto WRITEV = [&](const KVStage& st, int buf) {
#pragma unroll
        for (int it = 0; it < 2; ++it) {
            const int cb = scb + it * 4;
            const int phys = cb ^ (srow & 7);
            *(uint64_t*)&Vs[buf][srow * 64 + phys * 8] = st.rva[it];
            *(uint64_t*)&Vs[buf][srow * 64 + phys * 8 + 4] = st.rvb[it];
        }
    };

    constexpr int NT = S / 64;

    // One tile: QK(kf) -> prefetch kf(kt+1) -> softmax (mask from stX) ->
    // write tile kt+1 (stW) into Vs[buf^1] -> rowsum+PV from Vs[buf] ->
    // reload stX with tile kt+2 -> single barrier.
    auto DO_HALF = [&](int kt, int buf, KVStage& stW, KVStage& stX) {
        // --- QK^T (swapped): C col = q = l15, row = key = nt*16+quad*4+r ---
        f32x4 sa[2][4];
        __builtin_amdgcn_s_setprio(1);
#pragma unroll
        for (int mi = 0; mi < 2; ++mi)
#pragma unroll
            for (int nt = 0; nt < 4; ++nt) {
                f32x4 c = {0.f, 0.f, 0.f, 0.f};
                c = __builtin_amdgcn_mfma_f32_16x16x32_bf16(kf[nt][0], aq[mi][0], c, 0, 0, 0);
                c = __builtin_amdgcn_mfma_f32_16x16x32_bf16(kf[nt][1], aq[mi][1], c, 0, 0, 0);
                sa[mi][nt] = c;
            }
        __builtin_amdgcn_s_setprio(0);

        // kf dead now: prefetch next tile's K fragments (latency hidden below)
        if (kt + 1 < NT) KFLOAD(kt + 1);

        // --- softmax -> packed PV A-fragments, fully in registers ---
        bf16x8 ap[2][2];
#pragma unroll
        for (int mi = 0; mi < 2; ++mi) {
            const uint64_t mw = stX.rm[mi];
            const uint32_t mlo = (uint32_t)(mw >> (quad * 4));        // bits r,16+r: nt=0,1
            const uint32_t mhi = (uint32_t)(mw >> (quad * 4 + 32));   // bits r,16+r: nt=2,3
            uint32_t pk[4][2];
#pragma unroll
            for (int nt = 0; nt < 4; ++nt) {
                const uint32_t mx = (nt < 2) ? mlo : mhi;
                float p[4];
#pragma unroll
                for (int r = 0; r < 4; ++r) {
                    const float e = __builtin_amdgcn_exp2f(sa[mi][nt][r]);
                    p[r] = ((mx >> ((nt & 1) * 16 + r)) & 1u) ? e : 0.f;
                }
                pk[nt][0] = (uint32_t)f2bf_hw(p[0]) | ((uint32_t)f2bf_hw(p[1]) << 16);
                pk[nt][1] = (uint32_t)f2bf_hw(p[2]) | ((uint32_t)f2bf_hw(p[3]) << 16);
            }
            const u32x4 w0 = {pk[0][0], pk[0][1], pk[1][0], pk[1][1]};
            const u32x4 w1 = {pk[2][0], pk[2][1], pk[3][0], pk[3][1]};
            ap[mi][0] = __builtin_bit_cast(bf16x8, w0);
            ap[mi][1] = __builtin_bit_cast(bf16x8, w1);
        }

        // stage tile kt+1's V into the other LDS buffer (overlaps this compute;
        // buf^1's previous readers finished before the last barrier)
        if (kt + 1 < NT) WRITEV(stW, buf ^ 1);

        __builtin_amdgcn_s_setprio(1);
        // row sums (softmax denominator) -- key order irrelevant
#pragma unroll
        for (int mi = 0; mi < 2; ++mi) {
            Ol[mi] = __builtin_amdgcn_mfma_f32_16x16x32_bf16(ap[mi][0], ONES, Ol[mi], 0, 0, 0);
            Ol[mi] = __builtin_amdgcn_mfma_f32_16x16x32_bf16(ap[mi][1], ONES, Ol[mi], 0, 0, 0);
        }
        // PV: B-fragments from Vs[buf] in physical key order (matches ap)
#pragma unroll
        for (int dt = 0; dt < 4; ++dt) {
            const bf16x8 bv0 = *(const bf16x8*)&Vs[buf][(dt * 16 + l15) * 64 + (quad ^ r7) * 8];
            const bf16x8 bv1 = *(const bf16x8*)&Vs[buf][(dt * 16 + l15) * 64 + ((quad + 4) ^ r7) * 8];
#pragma unroll
            for (int mi = 0; mi < 2; ++mi) {
                O[mi][dt] = __builtin_amdgcn_mfma_f32_16x16x32_bf16(ap[mi][0], bv0, O[mi][dt], 0, 0, 0);
                O[mi][dt] = __builtin_amdgcn_mfma_f32_16x16x32_bf16(ap[mi][1], bv1, O[mi][dt], 0, 0, 0);
            }
        }
        __builtin_amdgcn_s_setprio(0);

        // refill stX with tile kt+2's V+mask (stX's mask was consumed above)
        if (kt + 2 < NT) LOADV(stX, kt + 2);

        asm volatile("s_waitcnt lgkmcnt(0)" ::: "memory");  // my ds_writes done
        __builtin_amdgcn_s_barrier();                        // V loads stay in flight
        __builtin_amdgcn_sched_barrier(0);
    };

    // --- prologue ---
    KVStage stA, stB;
    LOADV(stA, 0);
    KFLOAD(0);
    LOADV(stB, 1);
    WRITEV(stA, 0);                                          // waits on stA loads
    asm volatile("s_waitcnt lgkmcnt(0)" ::: "memory");
    __builtin_amdgcn_s_barrier();
    __builtin_amdgcn_sched_barrier(0);

    for (int kt = 0; kt < NT; kt += 2) {
        DO_HALF(kt, 0, stB, stA);       // compute kt; write kt+1; reload stA<-kt+2
        DO_HALF(kt + 1, 1, stA, stB);   // compute kt+1; write kt+2; reload stB<-kt+3
    }

    // Epilogue: normalize by row sum, write ctx bf16 [B,S,D].
#pragma unroll
    for (int mi = 0; mi < 2; ++mi) {
#pragma unroll
        for (int r = 0; r < 4; ++r) {
            const float inv = 1.f / Ol[mi][r];
            const int gm = mbase + q0 + wave * 32 + mi * 16 + quad * 4 + r;
#pragma unroll
            for (int dt = 0; dt < 4; ++dt)
                ctx[(size_t)gm * D + e0 + dt * 16 + l15] = f2bf(O[mi][dt][r] * inv);
        }
    }
}

// ---------------------------------------------------------------------------
extern "C" void kernel_launch(void* const* d_in, const int* in_sizes, int n_in,
                              void* d_out, int out_size, void* d_ws, size_t ws_size,
                              hipStream_t stream) {
    (void)in_sizes; (void)n_in; (void)out_size; (void)ws_size;
    const float* q = (const float*)d_in[0];
    const float* k = (const float*)d_in[1];
    const float* v = (const float*)d_in[2];
    const int* msk = (const int*)d_in[3];
    const float* w_q = (const float*)d_in[4];
    const float* w_k = (const float*)d_in[5];
    const float* w_v = (const float*)d_in[6];
    const float* w_o = (const float*)d_in[7];
    float* out = (float*)d_out;

    const size_t MB = 1u << 20;
    char* w = (char*)d_ws;
    u16* qb   = (u16*)(w + 0 * MB);     // 16 MB
    u16* kb   = (u16*)(w + 16 * MB);    // 16 MB
    u16* vb   = (u16*)(w + 32 * MB);    // 16 MB
    u16* wqb  = (u16*)(w + 48 * MB);    // 2 MB
    u16* wkb  = (u16*)(w + 50 * MB);    // 2 MB
    u16* wvb  = (u16*)(w + 52 * MB);    // 2 MB
    u16* wob  = (u16*)(w + 54 * MB);    // 2 MB
    uint64_t* maskb = (uint64_t*)(w + 56 * MB);  // 2 MB
    u16* Qf   = (u16*)(w + 58 * MB);    // 16 MB
    u16* Kf   = (u16*)(w + 74 * MB);    // 16 MB
    u16* Vtf  = (u16*)(w + 90 * MB);    // 16 MB
    u16* ctxb = (u16*)(w + 106 * MB);   // 16 MB

    // scale folded into Q projection: (1/sqrt(DK)) * log2(e)
    const float SCL2 = 0.18033688011112042f;

    dim3 blk(256);
    conv_bf16<<<dim3(8192, 3), blk, 0, stream>>>(q, k, v, q, qb, kb, vb, qb, M_TOT * D);
    conv_bf16<<<dim3(1024, 4), blk, 0, stream>>>(w_q, w_k, w_v, w_o, wqb, wkb, wvb, wob, D * D);
    mask_pack<<<dim3(S * S / 32 / 256), blk, 0, stream>>>(msk, (uint32_t*)maskb);

    gemm_bt<u16><<<dim3(M_TOT / 128, D / 128), blk, 0, stream>>>(qb, wqb, Qf, M_TOT, D, D, SCL2);
    gemm_bt<u16><<<dim3(M_TOT / 128, D / 128), blk, 0, stream>>>(kb, wkb, Kf, M_TOT, D, D, 1.0f);
    // V^T = w_v @ v^T : [D][M_TOT]
    gemm_bt<u16><<<dim3(D / 128, M_TOT / 128), blk, 0, stream>>>(wvb, vb, Vtf, D, M_TOT, D, 1.0f);

    attn_mfma<<<dim3(S / 128, B * H), blk, 0, stream>>>(Qf, Kf, Vtf, maskb, ctxb);

    gemm_bt<float><<<dim3(M_TOT / 128, D / 128), blk, 0, stream>>>(ctxb, wob, out, M_TOT, D, D, 1.0f);
}

// Round 5
// 494.795 us; speedup vs baseline: 1.2734x; 1.2734x over previous
//
#include <hip/hip_runtime.h>
#include <math.h>
#include <stdint.h>

constexpr int B = 2, S = 4096, D = 1024, H = 16, DK = 64;
constexpr int M_TOT = B * S; // 8192

typedef __attribute__((ext_vector_type(8))) short bf16x8;
typedef __attribute__((ext_vector_type(4))) float f32x4;
typedef __attribute__((ext_vector_type(4))) uint32_t u32x4;
typedef unsigned short u16;

// fp32 -> bf16 round-to-nearest-even (manual, always correct)
__device__ inline u16 f2bf(float f) {
    uint32_t u = __builtin_bit_cast(uint32_t, f);
    u += 0x7fffu + ((u >> 16) & 1u);
    return (u16)(u >> 16);
}

// fp32 -> bf16 via native __bf16 (gfx950 v_cvt_pk_bf16_f32 path)
__device__ inline u16 f2bf_hw(float f) {
    __bf16 h = (__bf16)f;
    return __builtin_bit_cast(u16, h);
}

// async global->LDS, 16B per lane. lds base must be wave-uniform.
__device__ inline void gl2lds16(const void* g, void* l) {
    __builtin_amdgcn_global_load_lds((const __attribute__((address_space(1))) void*)g,
                                     (__attribute__((address_space(3))) void*)l, 16, 0, 0);
}

// ---------------------------------------------------------------------------
// fp32 -> bf16 conversion; blockIdx.y selects tensor.
// ---------------------------------------------------------------------------
__global__ __launch_bounds__(256) void conv_bf16(const float* __restrict__ s0, const float* __restrict__ s1,
                                                 const float* __restrict__ s2, const float* __restrict__ s3,
                                                 u16* __restrict__ d0, u16* __restrict__ d1,
                                                 u16* __restrict__ d2, u16* __restrict__ d3, int n) {
    const float* s; u16* d;
    switch (blockIdx.y) {
        case 0: s = s0; d = d0; break;
        case 1: s = s1; d = d1; break;
        case 2: s = s2; d = d2; break;
        default: s = s3; d = d3; break;
    }
    const int i = (blockIdx.x * 256 + threadIdx.x) * 4;
    if (i < n) {
        float4 v = *(const float4*)(s + i);
        ushort4 o;
        o.x = f2bf(v.x); o.y = f2bf(v.y); o.z = f2bf(v.z); o.w = f2bf(v.w);
        *(ushort4*)(d + i) = o;
    }
}

// int32 mask [S,S] -> bitmask, bit c of u64 word (q*64+t) = mask[q][t*64+c]
__global__ __launch_bounds__(256) void mask_pack(const int* __restrict__ m, uint32_t* __restrict__ out) {
    const int i = blockIdx.x * 256 + threadIdx.x;  // one u32 = 32 keys
    const int base = i * 32;
    uint32_t b = 0;
#pragma unroll
    for (int j = 0; j < 32; ++j) b |= (m[base + j] != 0 ? 1u : 0u) << j;
    out[i] = b;
}

// ---------------------------------------------------------------------------
// bf16 GEMM core: Y[i][j] = oscale * sum_k X[i][k] * W[j][k]
// 128x128 tile, 4 waves in 2x2, BK=64, double-buffered LDS (T3 2-phase):
// STAGE(next) issued BEFORE COMPUTE(cur); vmcnt(0)+barrier AFTER compute so
// global_load_lds latency hides under the MFMAs.
// ---------------------------------------------------------------------------
template <typename OutT>
__device__ __forceinline__ void gemm_core(const u16* __restrict__ X, const u16* __restrict__ Wm,
                                          OutT* __restrict__ Y, int i0, int j0, int N, int K,
                                          float oscale, u16* As, u16* Bs) {
    const int tid = threadIdx.x;
    const int lane = tid & 63;
    const int wave = tid >> 6;
    const int l15 = lane & 15;
    const int quad = lane >> 4;
    const int wm = wave & 1, wn = wave >> 1;
    const int lr = lane >> 3;        // row within 8-row chunk
    const int lc = (lane & 7) * 8;   // k offset within 64

    f32x4 zero = {0.f, 0.f, 0.f, 0.f};
    f32x4 acc[4][4];
#pragma unroll
    for (int a = 0; a < 4; ++a)
#pragma unroll
        for (int b2 = 0; b2 < 4; ++b2) acc[a][b2] = zero;

    auto STAGE = [&](int buf, int k0) {
#pragma unroll
        for (int c = 0; c < 4; ++c) {
            const int ch = wave * 4 + c;          // 0..15
            const int row = ch * 8 + lr;          // 0..127
            gl2lds16(X + (size_t)(i0 + row) * K + k0 + lc, &As[buf * 8192 + ch * 512]);
            gl2lds16(Wm + (size_t)(j0 + row) * K + k0 + lc, &Bs[buf * 8192 + ch * 512]);
        }
    };

    auto COMPUTE = [&](int buf) {
        bf16x8 af[4][2];
#pragma unroll
        for (int mt = 0; mt < 4; ++mt)
#pragma unroll
            for (int ks = 0; ks < 2; ++ks)
                af[mt][ks] = *(const bf16x8*)&As[buf * 8192 + (wm * 64 + mt * 16 + l15) * 64 + ks * 32 + quad * 8];
#pragma unroll
        for (int nt = 0; nt < 4; ++nt) {
#pragma unroll
            for (int ks = 0; ks < 2; ++ks) {
                bf16x8 bfr = *(const bf16x8*)&Bs[buf * 8192 + (wn * 64 + nt * 16 + l15) * 64 + ks * 32 + quad * 8];
#pragma unroll
                for (int mt = 0; mt < 4; ++mt)
                    acc[mt][nt] = __builtin_amdgcn_mfma_f32_16x16x32_bf16(af[mt][ks], bfr, acc[mt][nt], 0, 0, 0);
            }
        }
    };

    const int KT = K >> 6;   // all call sites: K=1024 -> 16 (even)
    STAGE(0, 0);
    asm volatile("s_waitcnt vmcnt(0)" ::: "memory");
    __builtin_amdgcn_s_barrier();
    __builtin_amdgcn_sched_barrier(0);
    for (int t = 0; t < KT; t += 2) {
        if (t + 1 < KT) STAGE(1, (t + 1) << 6);
        COMPUTE(0);
        asm volatile("s_waitcnt vmcnt(0)" ::: "memory");
        __builtin_amdgcn_s_barrier();
        __builtin_amdgcn_sched_barrier(0);
        if (t + 2 < KT) STAGE(0, (t + 2) << 6);
        if (t + 1 < KT) {
            COMPUTE(1);
            asm volatile("s_waitcnt vmcnt(0)" ::: "memory");
            __builtin_amdgcn_s_barrier();
            __builtin_amdgcn_sched_barrier(0);
        }
    }

#pragma unroll
    for (int mt = 0; mt < 4; ++mt) {
#pragma unroll
        for (int r = 0; r < 4; ++r) {
            const int gi = i0 + wm * 64 + mt * 16 + quad * 4 + r;
#pragma unroll
            for (int nt = 0; nt < 4; ++nt) {
                const int gj = j0 + wn * 64 + nt * 16 + l15;
                const float v = acc[mt][nt][r] * oscale;
                if constexpr (sizeof(OutT) == 2) {
                    Y[(size_t)gi * N + gj] = (OutT)f2bf(v);
                } else {
                    Y[(size_t)gi * N + gj] = v;
                }
            }
        }
    }
}

template <typename OutT>
__global__ __launch_bounds__(256) void gemm_bt(const u16* __restrict__ X, const u16* __restrict__ Wm,
                                               OutT* __restrict__ Y, int N, int K, float oscale) {
    __shared__ u16 As[2 * 128 * 64];
    __shared__ u16 Bs[2 * 128 * 64];
    gemm_core<OutT>(X, Wm, Y, blockIdx.x * 128, blockIdx.y * 128, N, K, oscale, As, Bs);
}

// Fused QKV projections: one 1536-block launch (3x the waves/CU of a single
// 512-block GEMM) so the per-K-step barrier drains are hidden by cross-block
// TLP. blockIdx.z selects tensor; z=2 is the transposed V GEMM (i/j swapped).
__global__ __launch_bounds__(256) void gemm_qkv(const u16* __restrict__ qb, const u16* __restrict__ wqb,
                                                u16* __restrict__ Qf,
                                                const u16* __restrict__ kb, const u16* __restrict__ wkb,
                                                u16* __restrict__ Kf,
                                                const u16* __restrict__ wvb, const u16* __restrict__ vb,
                                                u16* __restrict__ Vtf, float scl2) {
    __shared__ u16 As[2 * 128 * 64];
    __shared__ u16 Bs[2 * 128 * 64];
    switch (blockIdx.z) {
        case 0:
            gemm_core<u16>(qb, wqb, Qf, blockIdx.x * 128, blockIdx.y * 128, D, D, scl2, As, Bs);
            break;
        case 1:
            gemm_core<u16>(kb, wkb, Kf, blockIdx.x * 128, blockIdx.y * 128, D, D, 1.0f, As, Bs);
            break;
        default:
            // V^T = w_v @ v^T : [D][M_TOT]
            gemm_core<u16>(wvb, vb, Vtf, blockIdx.y * 128, blockIdx.x * 128, M_TOT, D, 1.0f, As, Bs);
            break;
    }
}

// ---------------------------------------------------------------------------
// Flash attention, bf16 MFMA, static-shift softmax (p = exp2(s), shift
// cancels in 1/l normalize; row sums via all-ones MFMA column).
// Grid: (S/128, B*H). 4 waves; each wave owns 32 q-rows (2 m-frags).
//
// SWAPPED QK^T (S^T = mfma(K, Q)): lane holds P for one q-row (col = l15);
// packed bf16 pairs form the PV A-fragments directly (V's key dim bit-permuted
// in LDS: phys block cb holds keys {32*(cb>>2)+4*(cb&3)+0..3, +16..+19}).
// P never touches LDS.
//
// Staging/compute/swizzle are the round-2 measured-good forms (K AND V in LDS,
// phys = cb ^ (srow&7), V as two u64 writes). New this round: Ks/Vs double-
// buffered -> ONE lgkmcnt+barrier per tile (write t+1 into buf^1 overlaps
// compute of t; buf^1's readers finished at the previous barrier). T14 reg
// staging, no vmcnt drain in loop; T5 setprio; XCD-aware (q0,bh) remap.
// ---------------------------------------------------------------------------
struct KVStage {
    bf16x8 rk[2];
    uint64_t rva[2], rvb[2];
    uint64_t rm[2];
};

__global__ __launch_bounds__(256) void attn_mfma(const u16* __restrict__ Qb, const u16* __restrict__ Kb,
                                                 const u16* __restrict__ Vt,
                                                 const uint64_t* __restrict__ mask64,
                                                 u16* __restrict__ ctx) {
    __shared__ u16 Ks[2][64 * 64];       // [key][dk], col-blocks swizzled
    __shared__ u16 Vs[2][64 * 64];       // [dv][key], keys bit-permuted, col-blocks swizzled
    const int tid = threadIdx.x;
    const int lane = tid & 63;
    const int wave = tid >> 6;
    const int l15 = lane & 15;
    const int quad = lane >> 4;

    // XCD-aware remap: consecutive-dispatch blocks round-robin XCDs (bid&7);
    // give each XCD a contiguous group of 4 heads so K/V panels stay in its L2.
    const int bid = blockIdx.y * (S / 128) + blockIdx.x;   // 0..1023
    const int xcd = bid & 7;
    const int loc = bid >> 3;            // 0..127
    const int bh = xcd * 4 + (loc >> 5); // 0..31
    const int q0 = (loc & 31) * 128;

    const int bb = bh >> 4, hh = bh & 15;
    const int mbase = bb * S;
    const int e0 = hh * DK;
    const int r7 = l15 & 7;

    // staging mapping: thread -> (row, col-block)
    const int srow = tid >> 2;           // 0..63
    const int scb = tid & 3;             // 0..3 (+4 on second iter)

    // Q fragments (B-operand: col = l15 = q-row, k = dk). Q pre-scaled by
    // (1/sqrt(DK))*log2(e).
    bf16x8 aq[2][2];
#pragma unroll
    for (int mi = 0; mi < 2; ++mi) {
        const u16* qrow = Qb + (size_t)(mbase + q0 + wave * 32 + mi * 16 + l15) * D + e0;
        aq[mi][0] = *(const bf16x8*)(qrow + quad * 8);
        aq[mi][1] = *(const bf16x8*)(qrow + 32 + quad * 8);
    }

    f32x4 O[2][4];
    f32x4 Ol[2];
#pragma unroll
    for (int mi = 0; mi < 2; ++mi) {
        Ol[mi] = (f32x4){0.f, 0.f, 0.f, 0.f};
#pragma unroll
        for (int dt = 0; dt < 4; ++dt) O[mi][dt] = (f32x4){0.f, 0.f, 0.f, 0.f};
    }

    bf16x8 ONES;
#pragma unroll
    for (int i = 0; i < 8; ++i) ONES[i] = (short)0x3F80;  // bf16 1.0

    // one mask u64 per q-row per K-tile (lane's q-row = l15)
    const uint64_t* mrow[2];
#pragma unroll
    for (int mi = 0; mi < 2; ++mi)
        mrow[mi] = mask64 + (size_t)(q0 + wave * 32 + mi * 16 + l15) * (S / 64);

    auto LOADT = [&](KVStage& st, int kt) {
        const int kb = kt * 64;
#pragma unroll
        for (int it = 0; it < 2; ++it) {
            const int cb = scb + it * 4;
            st.rk[it] = *(const bf16x8*)(Kb + (size_t)(mbase + kb + srow) * D + e0 + cb * 8);
            const int k0v = 32 * (cb >> 2) + 4 * (cb & 3);
            const u16* vsrc = Vt + (size_t)(e0 + srow) * M_TOT + mbase + kb + k0v;
            st.rva[it] = *(const uint64_t*)(vsrc);
            st.rvb[it] = *(const uint64_t*)(vsrc + 16);
        }
#pragma unroll
        for (int mi = 0; mi < 2; ++mi) st.rm[mi] = mrow[mi][kt];
    };

    auto WRITET = [&](const KVStage& st, int buf) {
#pragma unroll
        for (int it = 0; it < 2; ++it) {
            const int cb = scb + it * 4;
            const int phys = cb ^ (srow & 7);
            *(bf16x8*)&Ks[buf][srow * 64 + phys * 8] = st.rk[it];
            *(uint64_t*)&Vs[buf][srow * 64 + phys * 8] = st.rva[it];
            *(uint64_t*)&Vs[buf][srow * 64 + phys * 8 + 4] = st.rvb[it];
        }
    };

    auto COMPUTE = [&](int buf, const KVStage& st) {
        // K A-fragments (row = key, k = dk), shared by both m-tiles.
        bf16x8 kf[4][2];
#pragma unroll
        for (int nt = 0; nt < 4; ++nt) {
            kf[nt][0] = *(const bf16x8*)&Ks[buf][(nt * 16 + l15) * 64 + (quad ^ r7) * 8];
            kf[nt][1] = *(const bf16x8*)&Ks[buf][(nt * 16 + l15) * 64 + ((quad + 4) ^ r7) * 8];
        }

        bf16x8 ap[2][2];  // [mi][ks]: PV A-fragments, built fully in registers
#pragma unroll
        for (int mi = 0; mi < 2; ++mi) {
            // Swapped QK^T: C col = q = l15, row = key = nt*16 + quad*4 + r.
            f32x4 sa[4];
            __builtin_amdgcn_s_setprio(1);
#pragma unroll
            for (int nt = 0; nt < 4; ++nt) {
                f32x4 c = {0.f, 0.f, 0.f, 0.f};
                c = __builtin_amdgcn_mfma_f32_16x16x32_bf16(kf[nt][0], aq[mi][0], c, 0, 0, 0);
                c = __builtin_amdgcn_mfma_f32_16x16x32_bf16(kf[nt][1], aq[mi][1], c, 0, 0, 0);
                sa[nt] = c;
            }
            __builtin_amdgcn_s_setprio(0);
            const uint64_t mw = st.rm[mi];
            const uint32_t mlo = (uint32_t)(mw >> (quad * 4));        // bits r, 16+r: nt=0,1
            const uint32_t mhi = (uint32_t)(mw >> (quad * 4 + 32));   // bits r, 16+r: nt=2,3
            uint32_t pk[4][2];
#pragma unroll
            for (int nt = 0; nt < 4; ++nt) {
                const uint32_t mx = (nt < 2) ? mlo : mhi;
                float p[4];
#pragma unroll
                for (int r = 0; r < 4; ++r) {
                    const float e = __builtin_amdgcn_exp2f(sa[nt][r]);
                    p[r] = ((mx >> ((nt & 1) * 16 + r)) & 1u) ? e : 0.f;
                }
                pk[nt][0] = (uint32_t)f2bf_hw(p[0]) | ((uint32_t)f2bf_hw(p[1]) << 16);
                pk[nt][1] = (uint32_t)f2bf_hw(p[2]) | ((uint32_t)f2bf_hw(p[3]) << 16);
            }
            // A-fragment assembly: key kappa lands at phys p = {k5,k3k2,k4,k1k0},
            // which is exactly register order {pk[2ks][0],pk[2ks][1],pk[2ks+1][0],pk[2ks+1][1]}.
            const u32x4 w0 = {pk[0][0], pk[0][1], pk[1][0], pk[1][1]};
            const u32x4 w1 = {pk[2][0], pk[2][1], pk[3][0], pk[3][1]};
            ap[mi][0] = __builtin_bit_cast(bf16x8, w0);
            ap[mi][1] = __builtin_bit_cast(bf16x8, w1);
        }

        __builtin_amdgcn_s_setprio(1);
        // row sums (softmax denominator) -- key order irrelevant
#pragma unroll
        for (int mi = 0; mi < 2; ++mi) {
            Ol[mi] = __builtin_amdgcn_mfma_f32_16x16x32_bf16(ap[mi][0], ONES, Ol[mi], 0, 0, 0);
            Ol[mi] = __builtin_amdgcn_mfma_f32_16x16x32_bf16(ap[mi][1], ONES, Ol[mi], 0, 0, 0);
        }
        // PV: B-fragments read physical key order, matching ap by construction.
#pragma unroll
        for (int dt = 0; dt < 4; ++dt) {
            const bf16x8 bv0 = *(const bf16x8*)&Vs[buf][(dt * 16 + l15) * 64 + (quad ^ r7) * 8];
            const bf16x8 bv1 = *(const bf16x8*)&Vs[buf][(dt * 16 + l15) * 64 + ((quad + 4) ^ r7) * 8];
#pragma unroll
            for (int mi = 0; mi < 2; ++mi) {
                O[mi][dt] = __builtin_amdgcn_mfma_f32_16x16x32_bf16(ap[mi][0], bv0, O[mi][dt], 0, 0, 0);
                O[mi][dt] = __builtin_amdgcn_mfma_f32_16x16x32_bf16(ap[mi][1], bv1, O[mi][dt], 0, 0, 0);
            }
        }
        __builtin_amdgcn_s_setprio(0);
    };

    constexpr int NT = S / 64;

    // --- main loop: LDS double-buffered, ONE barrier per tile ---
    KVStage stA, stB;
    LOADT(stA, 0);
    WRITET(stA, 0);                                          // waits on stA loads
    LOADT(stB, 1);                                           // in flight across barrier
    asm volatile("s_waitcnt lgkmcnt(0)" ::: "memory");
    __builtin_amdgcn_s_barrier();
    __builtin_amdgcn_sched_barrier(0);

    for (int kt = 0; kt < NT; kt += 2) {
        // tile kt from buf0; stage tile kt+1 into buf1 (readers of buf1 done
        // at the previous barrier); refill stA with kt+2.
        WRITET(stB, 1);
        COMPUTE(0, stA);
        if (kt + 2 < NT) LOADT(stA, kt + 2);
        asm volatile("s_waitcnt lgkmcnt(0)" ::: "memory");
        __builtin_amdgcn_s_barrier();
        __builtin_amdgcn_sched_barrier(0);

        // tile kt+1 from buf1; stage tile kt+2 into buf0; refill stB with kt+3.
        if (kt + 2 < NT) WRITET(stA, 0);
        COMPUTE(1, stB);
        if (kt + 3 < NT) LOADT(stB, kt + 3);
        asm volatile("s_waitcnt lgkmcnt(0)" ::: "memory");
        __builtin_amdgcn_s_barrier();
        __builtin_amdgcn_sched_barrier(0);
    }

    // Epilogue: normalize by row sum, write ctx bf16 [B,S,D].
#pragma unroll
    for (int mi = 0; mi < 2; ++mi) {
#pragma unroll
        for (int r = 0; r < 4; ++r) {
            const float inv = 1.f / Ol[mi][r];
            const int gm = mbase + q0 + wave * 32 + mi * 16 + quad * 4 + r;
#pragma unroll
            for (int dt = 0; dt < 4; ++dt)
                ctx[(size_t)gm * D + e0 + dt * 16 + l15] = f2bf(O[mi][dt][r] * inv);
        }
    }
}

// ---------------------------------------------------------------------------
extern "C" void kernel_launch(void* const* d_in, const int* in_sizes, int n_in,
                              void* d_out, int out_size, void* d_ws, size_t ws_size,
                              hipStream_t stream) {
    (void)in_sizes; (void)n_in; (void)out_size; (void)ws_size;
    const float* q = (const float*)d_in[0];
    const float* k = (const float*)d_in[1];
    const float* v = (const float*)d_in[2];
    const int* msk = (const int*)d_in[3];
    const float* w_q = (const float*)d_in[4];
    const float* w_k = (const float*)d_in[5];
    const float* w_v = (const float*)d_in[6];
    const float* w_o = (const float*)d_in[7];
    float* out = (float*)d_out;

    const size_t MB = 1u << 20;
    char* w = (char*)d_ws;
    u16* qb   = (u16*)(w + 0 * MB);     // 16 MB
    u16* kb   = (u16*)(w + 16 * MB);    // 16 MB
    u16* vb   = (u16*)(w + 32 * MB);    // 16 MB
    u16* wqb  = (u16*)(w + 48 * MB);    // 2 MB
    u16* wkb  = (u16*)(w + 50 * MB);    // 2 MB
    u16* wvb  = (u16*)(w + 52 * MB);    // 2 MB
    u16* wob  = (u16*)(w + 54 * MB);    // 2 MB
    uint64_t* maskb = (uint64_t*)(w + 56 * MB);  // 2 MB
    u16* Qf   = (u16*)(w + 58 * MB);    // 16 MB
    u16* Kf   = (u16*)(w + 74 * MB);    // 16 MB
    u16* Vtf  = (u16*)(w + 90 * MB);    // 16 MB
    u16* ctxb = (u16*)(w + 106 * MB);   // 16 MB

    // scale folded into Q projection: (1/sqrt(DK)) * log2(e)
    const float SCL2 = 0.18033688011112042f;

    dim3 blk(256);
    conv_bf16<<<dim3(8192, 3), blk, 0, stream>>>(q, k, v, q, qb, kb, vb, qb, M_TOT * D);
    conv_bf16<<<dim3(1024, 4), blk, 0, stream>>>(w_q, w_k, w_v, w_o, wqb, wkb, wvb, wob, D * D);
    mask_pack<<<dim3(S * S / 32 / 256), blk, 0, stream>>>(msk, (uint32_t*)maskb);

    // fused QKV projections: 1536 blocks (3x TLP of a single 512-block GEMM)
    gemm_qkv<<<dim3(M_TOT / 128, D / 128, 3), blk, 0, stream>>>(qb, wqb, Qf, kb, wkb, Kf, wvb, vb, Vtf, SCL2);

    attn_mfma<<<dim3(S / 128, B * H), blk, 0, stream>>>(Qf, Kf, Vtf, maskb, ctxb);

    gemm_bt<float><<<dim3(M_TOT / 128, D / 128), blk, 0, stream>>>(ctxb, wob, out, D, D, 1.0f);
}